// Round 3
// baseline (540.878 us; speedup 1.0000x reference)
//
#include <hip/hip_runtime.h>

// AvgSeq: out[b,s,d] = (sum_{t<=s} x[b,t,d]) / (s+1),  x: [16, 8192, 256] f32
//
// Single-pass chunked scan. Block (b,c) owns a CL=64-row chunk:
//   1. load chunk into registers (input read from HBM exactly ONCE)
//   2. publish chunk-sum vector to ws, set bit c in per-b atomic bitmask
//   3. wave 0 spins until all bits < c set, bulk-reads predecessor sums
//      (independent pipelined loads from the L2/LLC-resident 2 MiB agg array)
//   4. scan own chunk from registers, divide via rcp, store.
#define BB 16
#define SS 8192
#define DD 256
#define D4 64          // DD/4 float4 columns
#define NC 128         // chunks per batch row
#define CL 64          // SS/NC rows per chunk
#define RPT 16         // rows per thread (4 waves x 16 = CL)
#define NB (BB * NC)   // 2048 blocks

#define AGG_OFF 4096   // byte offset of agg[] in ws (masks live at offset 0)

__global__ __launch_bounds__(256) void avgseq_onepass(
    const float4* __restrict__ x, float4* __restrict__ out,
    unsigned long long* __restrict__ masks, float4* __restrict__ agg)
{
    const int blk = blockIdx.x;
    const int b   = blk >> 7;          // / NC
    const int c   = blk & (NC - 1);
    const int tid = threadIdx.x;
    const int col = tid & 63;          // float4 column
    const int q   = tid >> 6;          // wave id 0..3, owns rows q*16..q*16+15

    __shared__ float4 part[4][D4];
    __shared__ float4 pref[D4];

    const size_t rowbase = ((size_t)b * SS + (size_t)c * CL + (size_t)q * RPT) * D4 + col;
    const float4* p = x + rowbase;

    // 1. chunk rows into registers
    float4 v[RPT];
#pragma unroll
    for (int i = 0; i < RPT; ++i) v[i] = p[(size_t)i * D4];

    float4 ps = make_float4(0.f, 0.f, 0.f, 0.f);
#pragma unroll
    for (int i = 0; i < RPT; ++i) {
        ps.x += v[i].x; ps.y += v[i].y; ps.z += v[i].z; ps.w += v[i].w;
    }
    part[q][col] = ps;
    __syncthreads();

    if (q == 0) {
        // column sum over the whole chunk
        float4 s0 = part[0][col], s1 = part[1][col], s2 = part[2][col], s3 = part[3][col];
        float4 cs = make_float4(s0.x + s1.x + s2.x + s3.x,
                                s0.y + s1.y + s2.y + s3.y,
                                s0.z + s1.z + s2.z + s3.z,
                                s0.w + s1.w + s2.w + s3.w);
        // 2. publish aggregate, then set our bit (release)
        agg[(size_t)blk * D4 + col] = cs;
        __threadfence();
        if (col == 0) {
            __hip_atomic_fetch_or(&masks[b * 2 + (c >> 6)], 1ull << (c & 63),
                                  __ATOMIC_RELEASE, __HIP_MEMORY_SCOPE_AGENT);
        }
        // 3. wait for all predecessors, then bulk-accumulate their aggregates
        float4 run = make_float4(0.f, 0.f, 0.f, 0.f);
        if (c > 0) {
            const unsigned long long need0 =
                (c >= 64) ? ~0ull : ((1ull << c) - 1ull);
            const unsigned long long need1 =
                (c > 64) ? ((1ull << (c - 64)) - 1ull) : 0ull;
            for (;;) {
                unsigned long long m0 = __hip_atomic_load(&masks[b * 2 + 0],
                                       __ATOMIC_ACQUIRE, __HIP_MEMORY_SCOPE_AGENT);
                unsigned long long m1 = __hip_atomic_load(&masks[b * 2 + 1],
                                       __ATOMIC_ACQUIRE, __HIP_MEMORY_SCOPE_AGENT);
                if (((m0 & need0) == need0) && ((m1 & need1) == need1)) break;
                __builtin_amdgcn_s_sleep(2);
            }
            const float4* ap = agg + (size_t)(b * NC) * D4 + col;
            int cc = 0;
            for (; cc + 4 <= c; cc += 4) {
                float4 a0 = ap[(size_t)(cc + 0) * D4];
                float4 a1 = ap[(size_t)(cc + 1) * D4];
                float4 a2 = ap[(size_t)(cc + 2) * D4];
                float4 a3 = ap[(size_t)(cc + 3) * D4];
                run.x += (a0.x + a1.x) + (a2.x + a3.x);
                run.y += (a0.y + a1.y) + (a2.y + a3.y);
                run.z += (a0.z + a1.z) + (a2.z + a3.z);
                run.w += (a0.w + a1.w) + (a2.w + a3.w);
            }
            for (; cc < c; ++cc) {
                float4 a = ap[(size_t)cc * D4];
                run.x += a.x; run.y += a.y; run.z += a.z; run.w += a.w;
            }
        }
        pref[col] = run;
    }
    __syncthreads();

    // 4. per-thread start = block prefix + partials of earlier waves
    float4 start = pref[col];
    for (int qq = 0; qq < q; ++qq) {
        float4 t = part[qq][col];
        start.x += t.x; start.y += t.y; start.z += t.z; start.w += t.w;
    }

    const int sg0 = c * CL + q * RPT;
    float4* o = out + rowbase;
#pragma unroll
    for (int i = 0; i < RPT; ++i) {
        start.x += v[i].x; start.y += v[i].y; start.z += v[i].z; start.w += v[i].w;
        const float r = __builtin_amdgcn_rcpf((float)(sg0 + i + 1));
        o[(size_t)i * D4] = make_float4(start.x * r, start.y * r,
                                        start.z * r, start.w * r);
    }
}

extern "C" void kernel_launch(void* const* d_in, const int* in_sizes, int n_in,
                              void* d_out, int out_size, void* d_ws, size_t ws_size,
                              hipStream_t stream) {
    const float4* x = (const float4*)d_in[0];
    float4* out = (float4*)d_out;
    unsigned long long* masks = (unsigned long long*)d_ws;          // 16*2 u64
    float4* agg = (float4*)((char*)d_ws + AGG_OFF);                 // 2 MiB

    hipMemsetAsync(d_ws, 0, AGG_OFF, stream);   // zero the bitmasks (in-graph)
    avgseq_onepass<<<NB, 256, 0, stream>>>(x, out, masks, agg);
}